// Round 7
// baseline (106.904 us; speedup 1.0000x reference)
//
#include <hip/hip_runtime.h>

#define N_ 8
#define C_ 48
#define H_ 48
#define W_ 64
#define HO 384
#define WO 512
#define HW (H_*W_)   // 3072
#define CP 52        // padded channel dim in tin (52 dwords = 208B rows)

typedef float f32x4 __attribute__((ext_vector_type(4)));

// out[n][c][h*8+p][w*8+q] = sum_k softmax_k(mask[n][k*64+p*8+q][h][w]) * inp_pad[n][c][h+di-1][w+dj-1]
// Hybrid: taps staged in LDS [di][j][c] (c contiguous -> ds_read_b128 c-vectors),
// softmax weights computed per-thread in registers (mask rows 256B, read-once).
// One barrier total. Stores: 16B/lane, wave = 1024B contiguous.
__global__ __launch_bounds__(256, 3) void raft_up_kernel(
    const float* __restrict__ inp, const float* __restrict__ mask,
    float* __restrict__ out)
{
    __shared__ float tin[3 * 66 * CP];     // 41,184 B -> 3 blocks/CU

    const int t   = threadIdx.x;
    const int bid = blockIdx.x;            // (n*H + h)*4 + pg
    const int pg  = bid & 3;
    const int h   = (bid >> 2) % H_;
    const int n   = bid / (4 * H_);

    const int tq    = t & 127;
    const int chalf = t >> 7;              // 0: c 0..23, 1: c 24..47
    const int q4    = tq & 1;              // q quad (q = q4*4 + j)
    const int wi    = tq >> 1;             // 0..63 (w coordinate)

    // ---- softmax over 9 taps for my 8 planes (pl x 4 q's); f32x4 lanes = j (q)
    f32x4 w[2][9];
    {
        const float* mb = mask + ((size_t)n * 576 + pg * 16 + q4 * 4) * HW
                               + h * W_ + wi;
        #pragma unroll
        for (int pl = 0; pl < 2; ++pl)
            #pragma unroll
            for (int k = 0; k < 9; ++k)
                #pragma unroll
                for (int j = 0; j < 4; ++j)
                    w[pl][k][j] = mb[(size_t)(k * 64 + pl * 8 + j) * HW];

        #pragma unroll
        for (int pl = 0; pl < 2; ++pl) {
            f32x4 mx = w[pl][0];
            #pragma unroll
            for (int k = 1; k < 9; ++k) {
                mx.x = fmaxf(mx.x, w[pl][k].x); mx.y = fmaxf(mx.y, w[pl][k].y);
                mx.z = fmaxf(mx.z, w[pl][k].z); mx.w = fmaxf(mx.w, w[pl][k].w);
            }
            f32x4 s = (f32x4){0.f, 0.f, 0.f, 0.f};
            #pragma unroll
            for (int k = 0; k < 9; ++k) {
                f32x4 e;
                e.x = __expf(w[pl][k].x - mx.x);
                e.y = __expf(w[pl][k].y - mx.y);
                e.z = __expf(w[pl][k].z - mx.z);
                e.w = __expf(w[pl][k].w - mx.w);
                w[pl][k] = e;
                s += e;
            }
            f32x4 inv;
            inv.x = 1.f / s.x; inv.y = 1.f / s.y;
            inv.z = 1.f / s.z; inv.w = 1.f / s.w;
            #pragma unroll
            for (int k = 0; k < 9; ++k) w[pl][k] *= inv;
        }
    }

    // ---- stage input halo rows: tin[di][j][c] = inp[n][c][h+di-1][j-1]
    // j fastest across lanes -> coalesced global reads
    for (int e = t; e < 3 * C_ * 66; e += 256) {
        int j   = e % 66;
        int dc  = e / 66;
        int c   = dc % C_;
        int di  = dc / C_;
        int row = h + di - 1;
        int col = j - 1;
        float v = 0.f;
        if (row >= 0 && row < H_ && col >= 0 && col < W_)
            v = inp[((n * C_ + c) * H_ + row) * W_ + col];
        tin[(di * 66 + j) * CP + c] = v;
    }
    __syncthreads();

    float* outb = out + ((size_t)(n * C_ + chalf * 24) * HO + h * 8 + pg * 2) * WO
                      + wi * 8 + q4 * 4;

    for (int cblk = 0; cblk < 6; ++cblk) {
        const int c0 = chalf * 24 + cblk * 4;
        // taps as c-vectors: 9 x ds_read_b128, conflict-free (stride 52 dwords)
        f32x4 taps[9];
        #pragma unroll
        for (int di = 0; di < 3; ++di)
            #pragma unroll
            for (int dj = 0; dj < 3; ++dj)
                taps[di * 3 + dj] = *(const f32x4*)&tin[(di * 66 + wi + dj) * CP + c0];
        #pragma unroll
        for (int cc = 0; cc < 4; ++cc)
            #pragma unroll
            for (int pl = 0; pl < 2; ++pl) {
                f32x4 acc = w[pl][0] * taps[0][cc];
                #pragma unroll
                for (int k = 1; k < 9; ++k)
                    acc += w[pl][k] * taps[k][cc];
                *(f32x4*)(outb + ((size_t)(cblk * 4 + cc) * HO + pl) * WO) = acc;
            }
    }
}

extern "C" void kernel_launch(void* const* d_in, const int* in_sizes, int n_in,
                              void* d_out, int out_size, void* d_ws, size_t ws_size,
                              hipStream_t stream) {
    const float* inp  = (const float*)d_in[0];
    const float* mask = (const float*)d_in[1];
    float* out = (float*)d_out;
    const int blocks = N_ * H_ * 4;   // 8*48*4 = 1536
    raft_up_kernel<<<blocks, 256, 0, stream>>>(inp, mask, out);
}